// Round 3
// baseline (677.734 us; speedup 1.0000x reference)
//
#include <hip/hip_runtime.h>
#include <math.h>

// Problem constants: B=512, NQ=1, G=1000, H=8, IN=256, E=128, KD=16
#define GG    1000
#define HH    8
#define KDIM  16
#define EDIM  128
#define INDIM 256

// ---------------- K1: per-b  emb = din@Wemb^T + b ; Q = emb@Wq * 1/sqrt(KD) ----
__global__ __launch_bounds__(128) void k1_embq(
    const float* __restrict__ dIn,   // (B,256)
    const float* __restrict__ Wemb,  // (128,256)
    const float* __restrict__ bemb,  // (128)
    const float* __restrict__ Wq,    // (8,128,16)
    float* __restrict__ qout,        // ws: (B,128) = (B,H,KD)
    int B)
{
    const int b = blockIdx.x, t = threadIdx.x;
    __shared__ __align__(16) float s_din[INDIM];
    __shared__ float s_emb[EDIM];

    s_din[t]       = dIn[(size_t)b * INDIM + t];
    s_din[t + 128] = dIn[(size_t)b * INDIM + t + 128];
    __syncthreads();

    float acc = bemb[t];
    const float* w = Wemb + (size_t)t * INDIM;
    #pragma unroll 4
    for (int i = 0; i < INDIM; i += 4) {
        float4 wv = *(const float4*)(w + i);
        acc += wv.x * s_din[i] + wv.y * s_din[i + 1] +
               wv.z * s_din[i + 2] + wv.w * s_din[i + 3];
    }
    s_emb[t] = acc;
    __syncthreads();

    const int h = t >> 4, k = t & 15;
    float q = 0.f;
    const float* wq = Wq + (size_t)h * EDIM * KDIM + k;
    #pragma unroll 8
    for (int e = 0; e < EDIM; ++e) q += s_emb[e] * wq[e * KDIM];
    qout[(size_t)b * EDIM + t] = q * 0.25f;   // fold 1/sqrt(16)
}

// ---------------- K2: per-(h,b) attention -> heads[b, h*16+k] ----------------
__global__ __launch_bounds__(256) void k2_attn(
    const float* __restrict__ K,     // (8,B,1000,16)
    const float* __restrict__ V,     // (8,B,1000,16)
    const int*   __restrict__ mask,  // (B,1000)
    const float* __restrict__ qin,   // ws: (B,128)
    float* __restrict__ headsout,    // ws: (B,128)
    int B)
{
    const int bx = blockIdx.x;
    const int h = bx & 7, b = bx >> 3;   // 8 consecutive blocks share b -> mask L2 reuse
    const int t = threadIdx.x;

    __shared__ int   s_mask[GG];
    __shared__ float s_attn[GG];
    __shared__ __align__(16) float s_q[KDIM];
    __shared__ float s_red[8];
    __shared__ __align__(16) float s_hp[64][KDIM];
    __shared__ float s_bmax, s_binv;

    if (t < KDIM) s_q[t] = qin[(size_t)b * EDIM + h * KDIM + t];
    for (int g = t; g < GG; g += 256) s_mask[g] = mask[(size_t)b * GG + g];
    __syncthreads();

    // ---- compat: 4 rows/thread, all loads clustered before any LDS store ----
    const float* Kh = K + ((size_t)h * B + b) * (size_t)(GG * KDIM);
    float4 q0 = *(const float4*)&s_q[0];
    float4 q1 = *(const float4*)&s_q[4];
    float4 q2 = *(const float4*)&s_q[8];
    float4 q3 = *(const float4*)&s_q[12];

    float c[4];
    #pragma unroll
    for (int it = 0; it < 4; ++it) {
        const int g = t + it * 256;
        c[it] = -1e30f;
        if (g < GG && s_mask[g] != 0) {
            const float4* kp = (const float4*)(Kh + (size_t)g * KDIM);
            float4 k0 = kp[0], k1 = kp[1], k2 = kp[2], k3 = kp[3];
            float cc;
            cc  = q0.x * k0.x + q0.y * k0.y + q0.z * k0.z + q0.w * k0.w;
            cc += q1.x * k1.x + q1.y * k1.y + q1.z * k1.z + q1.w * k1.w;
            cc += q2.x * k2.x + q2.y * k2.y + q2.z * k2.z + q2.w * k2.w;
            cc += q3.x * k3.x + q3.y * k3.y + q3.z * k3.z + q3.w * k3.w;
            c[it] = cc;
        }
    }
    float lmax = -1e30f;
    #pragma unroll
    for (int it = 0; it < 4; ++it) {
        const int g = t + it * 256;
        if (g < GG) { s_attn[g] = c[it]; lmax = fmaxf(lmax, c[it]); }
    }

    // block max
    #pragma unroll
    for (int off = 32; off; off >>= 1) lmax = fmaxf(lmax, __shfl_xor(lmax, off));
    const int wid = t >> 6;
    if ((t & 63) == 0) s_red[wid] = lmax;
    __syncthreads();
    if (t == 0) s_bmax = fmaxf(fmaxf(s_red[0], s_red[1]), fmaxf(s_red[2], s_red[3]));
    __syncthreads();
    const float m = s_bmax;

    // exp + block sum (unrolled)
    float lsum = 0.f;
    #pragma unroll
    for (int it = 0; it < 4; ++it) {
        const int g = t + it * 256;
        if (g < GG) {
            float e = __expf(s_attn[g] - m);   // masked rows underflow to exactly 0
            s_attn[g] = e;
            lsum += e;
        }
    }
    #pragma unroll
    for (int off = 32; off; off >>= 1) lsum += __shfl_xor(lsum, off);
    if ((t & 63) == 0) s_red[4 + wid] = lsum;
    __syncthreads();
    if (t == 0) s_binv = 1.f / (s_red[4] + s_red[5] + s_red[6] + s_red[7]);
    __syncthreads();

    // ---- attn . V  (64 g-subgroups x 4 float4-slots), 4-way unrolled ----
    const int sub = t >> 2, k4 = t & 3;
    const float* Vh = V + ((size_t)h * B + b) * (size_t)(GG * KDIM) + k4 * 4;
    float4 acc = make_float4(0.f, 0.f, 0.f, 0.f);
    #pragma unroll 4
    for (int g = sub; g < GG; g += 64) {
        float a = s_attn[g];
        if (a != 0.f) {
            float4 v = *(const float4*)(Vh + (size_t)g * KDIM);
            acc.x = fmaf(a, v.x, acc.x); acc.y = fmaf(a, v.y, acc.y);
            acc.z = fmaf(a, v.z, acc.z); acc.w = fmaf(a, v.w, acc.w);
        }
    }
    s_hp[sub][k4 * 4 + 0] = acc.x;
    s_hp[sub][k4 * 4 + 1] = acc.y;
    s_hp[sub][k4 * 4 + 2] = acc.z;
    s_hp[sub][k4 * 4 + 3] = acc.w;
    __syncthreads();
    if (t < KDIM) {
        float s = 0.f;
        #pragma unroll
        for (int i = 0; i < 64; ++i) s += s_hp[i][t];
        headsout[(size_t)b * EDIM + h * KDIM + t] = s * s_binv;
    }
}

// ------------- K2.5: per-b ctx = heads@Wout ; q2 = ctx@WQ2 * 1/sqrt(E) -------
__global__ __launch_bounds__(128) void k25_proj(
    const float* __restrict__ headsin, // ws: (B,128)
    const float* __restrict__ Wout,    // (8,16,128) = (128,128)
    const float* __restrict__ WQ2,     // (128,128)
    float* __restrict__ q2out,         // ws: (B,128)
    int B)
{
    const int b = blockIdx.x, t = threadIdx.x;
    __shared__ float s_heads[EDIM];
    __shared__ float s_ctx[EDIM];

    s_heads[t] = headsin[(size_t)b * EDIM + t];
    __syncthreads();
    {
        float acc = 0.f;
        #pragma unroll 8
        for (int j = 0; j < EDIM; ++j) acc += s_heads[j] * Wout[(size_t)j * EDIM + t];
        s_ctx[t] = acc;
    }
    __syncthreads();
    {
        float acc = 0.f;
        #pragma unroll 8
        for (int e = 0; e < EDIM; ++e) acc += s_ctx[e] * WQ2[(size_t)e * EDIM + t];
        q2out[(size_t)b * EDIM + t] = acc * 0.08838834764831845f;  // 1/sqrt(128)
    }
}

// ------------- K3: per-(b, eighth) pure stream of Vout + tanh ---------------
__global__ __launch_bounds__(256) void k3_out(
    const float* __restrict__ Vout,    // (B,1000,128)
    const float* __restrict__ q2in,    // ws: (B,128)
    float* __restrict__ out,           // (B,1000)
    int B)
{
    const int bx = blockIdx.x;
    const int b = bx >> 3, chunk = bx & 7;
    const int t = threadIdx.x;
    const int lane = t & 31;
    const int rowid = t >> 5;  // 0..7

    float4 q = *(const float4*)(q2in + (size_t)b * EDIM + lane * 4);
    const float* Vo = Vout + (size_t)b * (size_t)(GG * EDIM) + lane * 4;
    const int g0 = chunk * (GG / 8);
    const int g1 = g0 + (GG / 8);

    // two rows in flight per iteration
    for (int g = g0 + rowid; g < g1; g += 16) {
        const int ga = g, gb = g + 8;
        float4 va = *(const float4*)(Vo + (size_t)ga * EDIM);
        float4 vb;
        bool hasb = (gb < g1);
        if (hasb) vb = *(const float4*)(Vo + (size_t)gb * EDIM);

        float aa = va.x * q.x + va.y * q.y + va.z * q.z + va.w * q.w;
        #pragma unroll
        for (int off = 16; off; off >>= 1) aa += __shfl_xor(aa, off, 32);
        if (lane == 0) out[(size_t)b * GG + ga] = 10.f * tanhf(aa);

        if (hasb) {
            float ab = vb.x * q.x + vb.y * q.y + vb.z * q.z + vb.w * q.w;
            #pragma unroll
            for (int off = 16; off; off >>= 1) ab += __shfl_xor(ab, off, 32);
            if (lane == 0) out[(size_t)b * GG + gb] = 10.f * tanhf(ab);
        }
    }
}

extern "C" void kernel_launch(void* const* d_in, const int* in_sizes, int n_in,
                              void* d_out, int out_size, void* d_ws, size_t ws_size,
                              hipStream_t stream) {
    const float* dIn  = (const float*)d_in[0];
    const float* K    = (const float*)d_in[1];
    const float* V    = (const float*)d_in[2];
    const float* Vout = (const float*)d_in[3];
    const int*   mask = (const int*)d_in[4];
    const float* Wemb = (const float*)d_in[5];
    const float* bemb = (const float*)d_in[6];
    const float* Wq   = (const float*)d_in[7];
    const float* Wout = (const float*)d_in[8];
    const float* WQ2  = (const float*)d_in[9];
    float* out = (float*)d_out;

    const int B = in_sizes[0] / INDIM;
    float* ws_q     = (float*)d_ws;                 // B*128 floats
    float* ws_heads = ws_q + (size_t)B * EDIM;      // B*128 floats
    float* ws_q2    = ws_heads + (size_t)B * EDIM;  // B*128 floats

    k1_embq <<<dim3(B),      dim3(128), 0, stream>>>(dIn, Wemb, bemb, Wq, ws_q, B);
    k2_attn <<<dim3(HH * B), dim3(256), 0, stream>>>(K, V, mask, ws_q, ws_heads, B);
    k25_proj<<<dim3(B),      dim3(128), 0, stream>>>(ws_heads, Wout, WQ2, ws_q2, B);
    k3_out  <<<dim3(B * 8),  dim3(256), 0, stream>>>(Vout, ws_q2, out, B);
}